// Round 9
// baseline (100.556 us; speedup 1.0000x reference)
//
#include <hip/hip_runtime.h>
#include <hip/hip_bf16.h>

// SpecAugment: out = (x + noise*0.04) masked by per-sample freq/time zero masks.
// x, noise: [B=128, C=3, F=128, T=1000] f32. f0/f_len: [B,2], t0/t_len: [B,2] i32.
// Memory-bound. R8 (flat 128B-aligned blocks) = 98.8us best. This round:
// same flat-aligned structure, 2 float4s/thread (block = 8192B chunk,
// 24000 blocks; thread t does base+t and base+t+256 — both wave accesses
// fully contiguous & aligned) to raise memory-request concurrency.

#define B 128
#define C 3
#define Fd 128
#define T 1000
#define NOISE_STD 0.04f

typedef float  f32x4 __attribute__((ext_vector_type(4)));
typedef int    i32x2 __attribute__((ext_vector_type(2)));

constexpr int ROWS       = B * C * Fd;        // 49152
constexpr int V4_PER_ROW = T / 4;             // 250
constexpr int NV4        = ROWS * V4_PER_ROW; // 12,288,000
constexpr int V4_PER_WG  = 512;               // 8192 B per block
constexpr int NBLOCKS    = NV4 / V4_PER_WG;   // 24000 exactly

__global__ __launch_bounds__(256) void specaug_kernel(
    const float* __restrict__ x, const float* __restrict__ noise,
    const int* __restrict__ f0, const int* __restrict__ f_len,
    const int* __restrict__ t0, const int* __restrict__ t_len,
    float* __restrict__ out)
{
    const int i0 = blockIdx.x * V4_PER_WG + threadIdx.x;  // flat float4 index
    int idx[2] = { i0, i0 + 256 };

    // Per-element state
    f32x4 xv[2], nv[2];
    bool fm[2];
    int  rem[2], bb[2];

#pragma unroll
    for (int j = 0; j < 2; ++j) {
        const int i = idx[j];
        const unsigned row = (unsigned)i / (unsigned)V4_PER_ROW;   // magic-mul
        rem[j] = i - (int)row * V4_PER_ROW;
        const int b = (int)(row / (unsigned)(C * Fd));
        const int f = (int)(row & (Fd - 1));
        bb[j] = b;

        const i32x2 fa = reinterpret_cast<const i32x2*>(f0)[b];
        const i32x2 fl = reinterpret_cast<const i32x2*>(f_len)[b];
        fm[j] = (f >= fa.x && f < fa.x + fl.x) ||
                (f >= fa.y && f < fa.y + fl.y);
    }

    // Issue all input loads back-to-back for max outstanding requests.
#pragma unroll
    for (int j = 0; j < 2; ++j) {
        if (!fm[j]) {
            xv[j] = reinterpret_cast<const f32x4*>(x)[idx[j]];
            nv[j] = reinterpret_cast<const f32x4*>(noise)[idx[j]];
        }
    }

#pragma unroll
    for (int j = 0; j < 2; ++j) {
        f32x4 ov = {0.f, 0.f, 0.f, 0.f};
        if (!fm[j]) {
            const i32x2 ta = reinterpret_cast<const i32x2*>(t0)[bb[j]];
            const i32x2 tl = reinterpret_cast<const i32x2*>(t_len)[bb[j]];
            const int t = rem[j] * 4;
#pragma unroll
            for (int k = 0; k < 4; ++k) {
                const int tt = t + k;
                const bool tmask = (tt >= ta.x && tt < ta.x + tl.x) ||
                                   (tt >= ta.y && tt < ta.y + tl.y);
                ov[k] = tmask ? 0.f : fmaf(nv[j][k], NOISE_STD, xv[j][k]);
            }
        }
        reinterpret_cast<f32x4*>(out)[idx[j]] = ov;
    }
}

extern "C" void kernel_launch(void* const* d_in, const int* in_sizes, int n_in,
                              void* d_out, int out_size, void* d_ws, size_t ws_size,
                              hipStream_t stream)
{
    const float* x     = (const float*)d_in[0];
    const float* noise = (const float*)d_in[1];
    const int*   f0    = (const int*)d_in[2];
    const int*   f_len = (const int*)d_in[3];
    const int*   t0    = (const int*)d_in[4];
    const int*   t_len = (const int*)d_in[5];
    float* out = (float*)d_out;

    specaug_kernel<<<NBLOCKS, 256, 0, stream>>>(x, noise, f0, f_len, t0, t_len, out);
}